// Round 5
// baseline (508.324 us; speedup 1.0000x reference)
//
#include <hip/hip_runtime.h>
#include <math.h>

// Problem constants
#define B_N 8192
#define K_N 2048
#define D_N 768
#define R_N 32

// d_out element offsets: [x_q_st | loss | indices | dc]
#define OUT_XQ   0L
#define OUT_LOSS 6291456L
#define OUT_IDX  6291457L
#define OUT_DC   6299649L   // odd -> dc/P rows are 4B-aligned only; k==3 (mod 4) is 16B-aligned

// ---------------- emb = A @ B (f64 accumulate), h_k = ||e_k||^2  [bitwise == R4]
// + folded BT pack (blocks 0..95): BT4[i*32+r] = float4(B[r][4i..4i+3]) ----------------
__global__ __launch_bounds__(256) void k_emb(const float* __restrict__ A,
                                             const float* __restrict__ Bm,
                                             float* __restrict__ emb,
                                             float* __restrict__ hf,
                                             float* __restrict__ BT) {
    int k = blockIdx.x, t = threadIdx.x;
    if (k < 96) {   // BT pack, independent of the rest
        int j = k * 256 + t;
        int i = j >> 7;
        int rc = j & 127;
        int r = rc >> 2, c = rc & 3;
        BT[j] = Bm[r * D_N + 4 * i + c];
    }
    __shared__ float a_s[R_N];
    if (t < R_N) a_s[t] = A[k * R_N + t];
    __syncthreads();
    double hpart = 0.0;
    for (int d = t; d < D_N; d += 256) {
        double e = 0.0;
#pragma unroll
        for (int r = 0; r < R_N; ++r) e += (double)a_s[r] * (double)Bm[r * D_N + d];
        float ef = (float)e;
        emb[(long)k * D_N + d] = ef;
        hpart += (double)ef * (double)ef;
    }
    __shared__ double red[256];
    red[t] = hpart; __syncthreads();
    for (int s = 128; s > 0; s >>= 1) { if (t < s) red[t] += red[t + s]; __syncthreads(); }
    if (t == 0) hf[k] = (float)red[0];
}

// ---------------- y = x @ B^T [bitwise == R4] + fused ||x_b||^2 (f64) ----------------
// R5: 16 rows/block, 2 rows per lane-half (2 accs) -> halves the 8x-redundant
// B-stream through LDS vs R4's 8-row blocks. xs 48 KB + bs 24 KB + normred 4 KB
// = 76 KB -> exactly 2 blocks/CU, 512 blocks fully resident in one round.
// Per-row FMA chain (i ascending via p*48+i, x/y/z/w) and norm order IDENTICAL
// to R4 -> y and A64 bitwise unchanged.
__global__ __launch_bounds__(256) void k_ygemm(const float* __restrict__ x,
                                               const float* __restrict__ BT,
                                               float* __restrict__ y,
                                               double* __restrict__ A64) {
    __shared__ __align__(16) float xs[16 * D_N];     // 48 KB
    __shared__ __align__(16) float bs[48 * 128];     // 24 KB = quarter of BT
    __shared__ double normred[16][32];
    int t = threadIdx.x;
    long b0 = (long)blockIdx.x * 16;
    int h = (t >> 5) & 1, r = t & 31, w = t >> 6;
    int ra = 2 * w + h;                              // 0..7; rows ra and ra+8

    // ---- stage x tile (contiguous 48 KB) + B quarter 0, async global->LDS ----
    const float* xsrc = x + b0 * D_N;
#pragma unroll
    for (int j = 0; j < 12; ++j) {
        __builtin_amdgcn_global_load_lds(
            (const __attribute__((address_space(1))) void*)(xsrc + j * 1024 + t * 4),
            (__attribute__((address_space(3))) void*)(xs + j * 1024 + t * 4),
            16, 0, 0);
    }
#pragma unroll
    for (int j = 0; j < 6; ++j) {
        __builtin_amdgcn_global_load_lds(
            (const __attribute__((address_space(1))) void*)(BT + j * 1024 + t * 4),
            (__attribute__((address_space(3))) void*)(bs + j * 1024 + t * 4),
            16, 0, 0);
    }
    __syncthreads();   // drains vmcnt(0) before any LDS read

    const float4* xa = (const float4*)(xs + ra * D_N);
    const float4* xb = (const float4*)(xs + (ra + 8) * D_N);
    const float4* bs4 = (const float4*)bs;
    float4 a0 = make_float4(0.f, 0.f, 0.f, 0.f);
    float4 a1 = make_float4(0.f, 0.f, 0.f, 0.f);

#pragma unroll 1
    for (int p = 0; p < 4; ++p) {
        if (p > 0) {
            __syncthreads();   // previous compute done reading bs
#pragma unroll
            for (int j = 0; j < 6; ++j) {
                __builtin_amdgcn_global_load_lds(
                    (const __attribute__((address_space(1))) void*)(BT + p * 6144 + j * 1024 + t * 4),
                    (__attribute__((address_space(3))) void*)(bs + j * 1024 + t * 4),
                    16, 0, 0);
            }
            __syncthreads();   // drain staging
        }
#pragma unroll
        for (int i = 0; i < 48; ++i) {
            float4 bb = bs4[i * 32 + r];
            float4 x0 = xa[p * 48 + i];
            float4 x1 = xb[p * 48 + i];
            a0.x = fmaf(x0.x, bb.x, a0.x); a0.y = fmaf(x0.y, bb.y, a0.y);
            a0.z = fmaf(x0.z, bb.z, a0.z); a0.w = fmaf(x0.w, bb.w, a0.w);
            a1.x = fmaf(x1.x, bb.x, a1.x); a1.y = fmaf(x1.y, bb.y, a1.y);
            a1.z = fmaf(x1.z, bb.z, a1.z); a1.w = fmaf(x1.w, bb.w, a1.w);
        }
    }
    y[(b0 + ra) * R_N + r] = (a0.x + a0.y) + (a0.z + a0.w);
    y[(b0 + ra + 8) * R_N + r] = (a1.x + a1.y) + (a1.z + a1.w);

    // xnorm partials from LDS (same bits as global x): (row,r) sums d = r+32q, q
    // ascending; then serial r2-ascending combine — chain order IDENTICAL to R4.
    const float* xr0 = xs + ra * D_N + r;
    const float* xr1 = xs + (ra + 8) * D_N + r;
    double nv0 = 0.0, nv1 = 0.0;
#pragma unroll
    for (int q = 0; q < 24; ++q) {
        double v0 = (double)xr0[32 * q];
        double v1 = (double)xr1[32 * q];
        nv0 += v0 * v0; nv1 += v1 * v1;
    }
    normred[ra][r] = nv0; normred[ra + 8][r] = nv1;
    __syncthreads();
    if (t < 16) {
        double s = 0.0;
#pragma unroll
        for (int r2 = 0; r2 < 32; ++r2) s += normred[t][r2];
        A64[b0 + t] = s;
    }
}

// ---------------- P[b,k] = h_k - 2 y_b.A_k + fused min/max partials  [bitwise == R4] ----------------
__global__ __launch_bounds__(256) void k_pgemm(const float* __restrict__ Am,
                                               const float* __restrict__ y,
                                               const float* __restrict__ hf,
                                               const double* __restrict__ A64,
                                               float* __restrict__ P,
                                               double* __restrict__ mmpart) {
    __shared__ float As[256][33];
    __shared__ float ys[32][32];
    __shared__ double a64s[32];
    __shared__ double smn[256], smx[256];
    int t = threadIdx.x;
    int k0 = blockIdx.x * 256, b0 = blockIdx.y * 32;
    for (int i = t; i < 256 * 32; i += 256) As[i >> 5][i & 31] = Am[(long)(k0 + (i >> 5)) * R_N + (i & 31)];
    for (int i = t; i < 32 * 32; i += 256) ys[i >> 5][i & 31] = y[(long)(b0 + (i >> 5)) * R_N + (i & 31)];
    if (t < 32) a64s[t] = A64[b0 + t];
    __syncthreads();
    int k = k0 + t;
    float ar[32];
#pragma unroll
    for (int r = 0; r < 32; ++r) ar[r] = As[t][r];
    float hk = hf[k];
    double mn = 1e300, mx = -1e300;
#pragma unroll 4
    for (int b = 0; b < 32; ++b) {
        float dot = 0.f;
#pragma unroll
        for (int r = 0; r < 32; ++r) dot = fmaf(ys[b][r], ar[r], dot);
        float p = fmaf(-2.f, dot, hk);
        P[(long)(b0 + b) * K_N + k] = p;
        double dv = a64s[b] + (double)p;
        mn = fmin(mn, dv); mx = fmax(mx, dv);
    }
    smn[t] = mn; smx[t] = mx; __syncthreads();
    for (int s = 128; s > 0; s >>= 1) {
        if (t < s) { smn[t] = fmin(smn[t], smn[t + s]); smx[t] = fmax(smx[t], smx[t + s]); }
        __syncthreads();
    }
    if (t == 0) {
        int bid = blockIdx.y * gridDim.x + blockIdx.x;
        mmpart[2 * bid] = smn[0]; mmpart[2 * bid + 1] = smx[0];
    }
}

// ---------------- minmax reduce -> sc  [== R4 values; gamma init moved to k_colsum] ----------------
__global__ __launch_bounds__(256) void k_minmax2(const double* __restrict__ part,
                                                 double* __restrict__ sc, int nblk) {
    int t = threadIdx.x;
    double mn = 1e300, mx = -1e300;
    for (int i = t; i < nblk; i += 256) {
        mn = fmin(mn, part[2 * i]); mx = fmax(mx, part[2 * i + 1]);
    }
    __shared__ double smn[256], smx[256];
    smn[t] = mn; smx[t] = mx; __syncthreads();
    for (int s = 128; s > 0; s >>= 1) {
        if (t < s) { smn[t] = fmin(smn[t], smn[t + s]); smx[t] = fmax(smx[t], smx[t + s]); }
        __syncthreads();
    }
    if (t == 0) {
        double mid = (smx[0] + smn[0]) * 0.5;
        double ampl = smx[0] - mid + 1e-5;
        sc[0] = mid; sc[1] = ampl; sc[2] = smn[0];
        sc[3] = 1.0 / (0.01 * ampl);   // beta
    }
}

// ---------------- first colsum (c0), gamma computed in-block  [bitwise == R4] ----------------
// gs[j] = (float)(beta * (mn - A64[b0+j])) — same f64 formula as the old k_minmax2
// gamma loop -> identical bits, computed redundantly per kx-block (64 f64 ops, trivial).
__global__ __launch_bounds__(256) void k_colsum(const float* __restrict__ P,
                                                const double* __restrict__ A64,
                                                const double* __restrict__ sc,
                                                float* __restrict__ part) {
    __shared__ float gs[64];
    int t = threadIdx.x;
    int k = blockIdx.x * 256 + t;
    int b0 = blockIdx.y * 64;
    if (t < 64) {
        double bet = sc[3], mnv = sc[2];
        gs[t] = (float)(bet * (mnv - A64[b0 + t]));
    }
    __syncthreads();
    float betaf = (float)sc[3];
    float s0 = 0.f, s1 = 0.f, s2 = 0.f, s3 = 0.f;
#pragma unroll
    for (int j = 0; j < 64; j += 4) {
        s0 += __expf(gs[j]     - betaf * P[(long)(b0 + j)     * K_N + k]);
        s1 += __expf(gs[j + 1] - betaf * P[(long)(b0 + j + 1) * K_N + k]);
        s2 += __expf(gs[j + 2] - betaf * P[(long)(b0 + j + 2) * K_N + k]);
        s3 += __expf(gs[j + 3] - betaf * P[(long)(b0 + j + 3) * K_N + k]);
    }
    part[(long)blockIdx.y * K_N + k] = (s0 + s1) + (s2 + s3);
}

__global__ __launch_bounds__(256) void k_colsum2(const float* __restrict__ part,
                                                 double* __restrict__ lnr64,
                                                 float* __restrict__ lnrf) {
    int k = blockIdx.x * 256 + threadIdx.x;
    double s = 0.0;
#pragma unroll 4
    for (int c = 0; c < 128; ++c) s += (double)part[(long)c * K_N + k];
    double l = -log(s);
    lnr64[k] = l; lnrf[k] = (float)l;
}

// ---------------- fused rowsum_i + colsum_{i+1}: ONE pass over P ----------------
// R5: 4-row batching. Per group of 4 rows: 4 independent load+exp+shfl chains (ILP),
// ONE barrier (double-buffered wred), 4 independent f64 logs, colsum accum from regs.
// 4 barriers/block-pass instead of 32; add/shfl/log orders unchanged -> bitwise == R4.
__global__ __launch_bounds__(512) void k_fused(const float* __restrict__ P,
                                               const float* __restrict__ lnrf,
                                               const double* __restrict__ sc,
                                               float* __restrict__ part) {
    __shared__ double wred[2][8][4];
    int t = threadIdx.x, l = t & 63, w = t >> 6;
    float betaf = (float)sc[3];
    int kbase = 3 + 4 * t;
    float ln0, ln1, ln2, ln3;
    if (t < 511) { ln0 = lnrf[kbase]; ln1 = lnrf[kbase + 1]; ln2 = lnrf[kbase + 2]; ln3 = lnrf[kbase + 3]; }
    else         { ln0 = lnrf[0];     ln1 = lnrf[1];         ln2 = lnrf[2];         ln3 = lnrf[2047]; }
    float4 acc = make_float4(0.f, 0.f, 0.f, 0.f);
    long rowbase = (long)blockIdx.x * 16;
#pragma unroll
    for (int g = 0; g < 4; ++g) {
        const int buf = g & 1;
        float4 pv[4];
#pragma unroll
        for (int j = 0; j < 4; ++j) {
            const float* row = P + (rowbase + 4 * g + j) * K_N;
            if (t < 511) {
                pv[j] = *(const float4*)(row + kbase);
            } else {
                pv[j].x = row[0]; pv[j].y = row[1]; pv[j].z = row[2]; pv[j].w = row[2047];
            }
        }
        double s[4];
#pragma unroll
        for (int j = 0; j < 4; ++j) {
            float e0 = __expf(ln0 - betaf * pv[j].x);
            float e1 = __expf(ln1 - betaf * pv[j].y);
            float e2 = __expf(ln2 - betaf * pv[j].z);
            float e3 = __expf(ln3 - betaf * pv[j].w);
            s[j] = (double)((e0 + e1) + (e2 + e3));
        }
#pragma unroll
        for (int off = 1; off < 64; off <<= 1) {
#pragma unroll
            for (int j = 0; j < 4; ++j) s[j] += __shfl_xor(s[j], off, 64);
        }
        if (l == 0) {
#pragma unroll
            for (int j = 0; j < 4; ++j) wred[buf][w][j] = s[j];
        }
        __syncthreads();
        // WAR across groups is safe: group g+2 rewrites wred[buf] only after the
        // g+1 barrier, which all threads reach only after finishing g's reads.
#pragma unroll
        for (int j = 0; j < 4; ++j) {
            double ss = ((wred[buf][0][j] + wred[buf][1][j]) + (wred[buf][2][j] + wred[buf][3][j]))
                      + ((wred[buf][4][j] + wred[buf][5][j]) + (wred[buf][6][j] + wred[buf][7][j]));
            float gf = (float)(-log(ss));
            acc.x += __expf(gf - betaf * pv[j].x);
            acc.y += __expf(gf - betaf * pv[j].y);
            acc.z += __expf(gf - betaf * pv[j].z);
            acc.w += __expf(gf - betaf * pv[j].w);
        }
    }
    // slot layout: t<511 -> slots 4t..4t+3 (k=3+4t..); t=511 -> slots 2044..2047 (k=0,1,2,2047)
    ((float4*)(part + (long)blockIdx.x * K_N))[t] = acc;
}

// reduce fused partials -> lnr (wave per k, deterministic)
__global__ __launch_bounds__(512) void k_freduce(const float* __restrict__ part,
                                                 double* __restrict__ lnr64,
                                                 float* __restrict__ lnrf) {
    int t = threadIdx.x, l = t & 63, w = t >> 6;
    int k = blockIdx.x * 8 + w;
    int slot = (k >= 3 && k < 2047) ? (k - 3) : (k < 3 ? 2044 + k : 2047);
    double s = 0.0;
#pragma unroll
    for (int j = 0; j < 8; ++j)
        s += (double)part[(long)(l + 64 * j) * K_N + slot];
#pragma unroll
    for (int off = 1; off < 64; off <<= 1) s += __shfl_xor(s, off, 64);
    if (l == 0) { double v = -log(s); lnr64[k] = v; lnrf[k] = (float)v; }
}

// ---------------- final: wave per row — hoisted loads, argmax(f64), dc in place,
// loss via ||e-x||^2 = A64[b] + P[b,bi] (P recovered from dec), gather emb ----------------
__global__ __launch_bounds__(512) void k_final(const double* __restrict__ lnr64,
                                               const double* __restrict__ sc,
                                               const double* __restrict__ A64,
                                               const float* __restrict__ emb,
                                               float* __restrict__ out,
                                               double* __restrict__ lossp) {
    int t = threadIdx.x, l = t & 63, w = t >> 6;
    long b = (long)blockIdx.x * 8 + w;
    float* row = out + OUT_DC + b * K_N;     // P in, dc out (disjoint per wave)
    double beta = sc[3], mid = sc[0], inva = 1.0 / sc[1];
    double a64b = A64[b];
    // ---- hoist ALL loads before any store (avoid alias serialization) ----
    float pe = 0.f;
    if (l < 3)   pe = row[l];
    if (l == 63) pe = row[2047];
    float4 pv[8];
#pragma unroll
    for (int c = 0; c < 8; ++c) {
        int i = l + 64 * c;
        if (i < 511) pv[c] = *(const float4*)(row + 3 + 4 * i);
    }
    // ---- argmax (in-lane ascending k -> first-max) + dc stores ----
    double best = -1e300; int bi = 1 << 30;
    if (l < 3) {
        double p = (double)pe;
        double dec = lnr64[l] - beta * p;
        if (dec > best) { best = dec; bi = l; }
        row[l] = (float)((a64b + p - mid) * inva);
    }
#pragma unroll
    for (int c = 0; c < 8; ++c) {
        int i = l + 64 * c;
        if (i < 511) {
            int k = 3 + 4 * i;
            double p0 = pv[c].x, p1 = pv[c].y, p2 = pv[c].z, p3 = pv[c].w;
            double d0 = lnr64[k] - beta * p0;
            double d1 = lnr64[k + 1] - beta * p1;
            double d2 = lnr64[k + 2] - beta * p2;
            double d3 = lnr64[k + 3] - beta * p3;
            if (d0 > best) { best = d0; bi = k; }
            if (d1 > best) { best = d1; bi = k + 1; }
            if (d2 > best) { best = d2; bi = k + 2; }
            if (d3 > best) { best = d3; bi = k + 3; }
            float4 dcv;
            dcv.x = (float)((a64b + p0 - mid) * inva);
            dcv.y = (float)((a64b + p1 - mid) * inva);
            dcv.z = (float)((a64b + p2 - mid) * inva);
            dcv.w = (float)((a64b + p3 - mid) * inva);
            *(float4*)(row + k) = dcv;
        }
    }
    if (l == 63) {
        double p = (double)pe;
        double dec = lnr64[2047] - beta * p;
        if (dec > best) { best = dec; bi = 2047; }
        row[2047] = (float)((a64b + p - mid) * inva);
    }
#pragma unroll
    for (int off = 1; off < 64; off <<= 1) {                   // first-max: min idx on ties
        double ov = __shfl_xor(best, off, 64);
        int oi = __shfl_xor(bi, off, 64);
        if (ov > best || (ov == best && oi < bi)) { best = ov; bi = oi; }
    }
    if (l == 0) {
        out[OUT_IDX + b] = (float)bi;
        // ||e_bi - x_b||^2 = A64[b] + P[b,bi]; P recovered: dec = lnr - beta*P
        double prec = (lnr64[bi] - best) / beta;
        lossp[b] = a64b + prec;
    }
    // gather emb -> x_q
    const float4* E4 = (const float4*)(emb + (long)bi * D_N);
    float4* O4 = (float4*)(out + OUT_XQ + b * D_N);
#pragma unroll
    for (int i = 0; i < 3; ++i) O4[i * 64 + l] = E4[i * 64 + l];
}

__global__ __launch_bounds__(1024) void k_loss2(const double* __restrict__ lossp,
                                                float* __restrict__ out) {
    __shared__ double red[1024];
    int t = threadIdx.x;
    double s = 0.0;
#pragma unroll
    for (int j = 0; j < 8; ++j) s += lossp[t + 1024 * j];
    red[t] = s; __syncthreads();
    for (int st = 512; st > 0; st >>= 1) { if (t < st) red[t] += red[t + st]; __syncthreads(); }
    if (t == 0) out[OUT_LOSS] = (float)(red[0] * 1.25 / (double)((long)B_N * D_N));
}

extern "C" void kernel_launch(void* const* d_in, const int* in_sizes, int n_in,
                              void* d_out, int out_size, void* d_ws, size_t ws_size,
                              hipStream_t stream) {
    const float* x  = (const float*)d_in[0];   // [8192,768]
    const float* Am = (const float*)d_in[1];   // [2048,32]
    const float* Bm = (const float*)d_in[2];   // [32,768]
    float* out = (float*)d_out;
    float* P = out + OUT_DC;                   // P lives in dc region; k_final converts in place

    char* ws = (char*)d_ws;
    float*  emb     = (float*)(ws);                 // 6,291,456 B
    // 4 MB pool at +6291456: y (1 MB, dead after pgemm) | cs_part (1 MB, dead after c0's
    // colsum2) | 2 MB spare — reused as fpart [512][2048] f32 by k_fused/k_freduce.
    // BT (96 KB) overlays the cs_part region: written inside k_emb, dead after k_ygemm,
    // long before k_colsum first writes cs_part.
    float*  y       = (float*)(ws + 6291456);       // 1,048,576 B
    float*  cs_part = (float*)(ws + 7340032);       // 128*2048*4 = 1,048,576 B
    float*  BTg     = (float*)(ws + 7340032);       // 98,304 B (overlays cs_part)
    float*  fpart   = (float*)(ws + 6291456);       // 512*2048*4 = 4,194,304 B (overlays y+cs_part)
    double* A64     = (double*)(ws + 10485760);     // 65,536 B
    float*  hf      = (float*)(ws + 10551296);      // 8,192 B
    double* lnr64   = (double*)(ws + 10592256);     // 16,384 B
    float*  lnrf    = (float*)(ws + 10608640);      // 8,192 B
    double* mmpart  = (double*)(ws + 10616832);     // 2048*2*8 = 32,768 B
    double* sc      = (double*)(ws + 10649600);     // 4 doubles
    double* lossp   = (double*)(ws + 10649856);     // 8192*8 = 65,536 B
    // total ws use ~10.7 MB

    k_emb<<<K_N, 256, 0, stream>>>(Am, Bm, emb, hf, BTg);
    k_ygemm<<<B_N / 16, 256, 0, stream>>>(x, BTg, y, A64);

    dim3 gp(K_N / 256, B_N / 32);
    k_pgemm<<<gp, 256, 0, stream>>>(Am, y, hf, A64, P, mmpart);
    k_minmax2<<<1, 256, 0, stream>>>(mmpart, sc, 2048);

    // c0 (colsum with gamma0), then 5 fused (rowsum_i + colsum_{i+1}) passes:
    // total colsum x6 / rowsum x5 == R4's schedule; contraction ~0.022/cycle,
    // residual ~2e-10 << ~1e-6 decision gap.
    dim3 ga(K_N / 256, 128);
    k_colsum<<<ga, 256, 0, stream>>>(P, A64, sc, cs_part);
    k_colsum2<<<K_N / 256, 256, 0, stream>>>(cs_part, lnr64, lnrf);
    for (int it = 0; it < 5; ++it) {
        k_fused<<<512, 512, 0, stream>>>(P, lnrf, sc, fpart);
        k_freduce<<<256, 512, 0, stream>>>(fpart, lnr64, lnrf);
    }

    k_final<<<B_N / 8, 512, 0, stream>>>(lnr64, sc, A64, emb, out, lossp);
    k_loss2<<<1, 1024, 0, stream>>>(lossp, out);
}

// Round 6
// 388.283 us; speedup vs baseline: 1.3092x; 1.3092x over previous
//
#include <hip/hip_runtime.h>
#include <math.h>

// Problem constants
#define B_N 8192
#define K_N 2048
#define D_N 768
#define R_N 32

// d_out element offsets: [x_q_st | loss | indices | dc]
#define OUT_XQ   0L
#define OUT_LOSS 6291456L
#define OUT_IDX  6291457L
#define OUT_DC   6299649L   // odd -> dc/P rows are 4B-aligned only; k==3 (mod 4) is 16B-aligned

// ---------------- emb = A @ B (f64 accumulate), h_k = ||e_k||^2  [bitwise == R4]
// + folded BT pack (blocks 0..95): BT4[i*32+r] = float4(B[r][4i..4i+3]) ----------------
__global__ __launch_bounds__(256) void k_emb(const float* __restrict__ A,
                                             const float* __restrict__ Bm,
                                             float* __restrict__ emb,
                                             float* __restrict__ hf,
                                             float* __restrict__ BT) {
    int k = blockIdx.x, t = threadIdx.x;
    if (k < 96) {   // BT pack, independent of the rest
        int j = k * 256 + t;
        int i = j >> 7;
        int rc = j & 127;
        int r = rc >> 2, c = rc & 3;
        BT[j] = Bm[r * D_N + 4 * i + c];
    }
    __shared__ float a_s[R_N];
    if (t < R_N) a_s[t] = A[k * R_N + t];
    __syncthreads();
    double hpart = 0.0;
    for (int d = t; d < D_N; d += 256) {
        double e = 0.0;
#pragma unroll
        for (int r = 0; r < R_N; ++r) e += (double)a_s[r] * (double)Bm[r * D_N + d];
        float ef = (float)e;
        emb[(long)k * D_N + d] = ef;
        hpart += (double)ef * (double)ef;
    }
    __shared__ double red[256];
    red[t] = hpart; __syncthreads();
    for (int s = 128; s > 0; s >>= 1) { if (t < s) red[t] += red[t + s]; __syncthreads(); }
    if (t == 0) hf[k] = (float)red[0];
}

// ---------------- y = x @ B^T [bitwise == R4] + fused ||x_b||^2 (f64) ----------------
// 16 rows/block, 2 rows per lane-half (2 accs); x + B quarters staged via
// global_load_lds. Per-row FMA chain (i ascending via p*48+i, x/y/z/w) and norm
// order IDENTICAL to R4 -> y and A64 bitwise unchanged.
__global__ __launch_bounds__(256) void k_ygemm(const float* __restrict__ x,
                                               const float* __restrict__ BT,
                                               float* __restrict__ y,
                                               double* __restrict__ A64) {
    __shared__ __align__(16) float xs[16 * D_N];     // 48 KB
    __shared__ __align__(16) float bs[48 * 128];     // 24 KB = quarter of BT
    __shared__ double normred[16][32];
    int t = threadIdx.x;
    long b0 = (long)blockIdx.x * 16;
    int h = (t >> 5) & 1, r = t & 31, w = t >> 6;
    int ra = 2 * w + h;                              // 0..7; rows ra and ra+8

    // ---- stage x tile (contiguous 48 KB) + B quarter 0, async global->LDS ----
    const float* xsrc = x + b0 * D_N;
#pragma unroll
    for (int j = 0; j < 12; ++j) {
        __builtin_amdgcn_global_load_lds(
            (const __attribute__((address_space(1))) void*)(xsrc + j * 1024 + t * 4),
            (__attribute__((address_space(3))) void*)(xs + j * 1024 + t * 4),
            16, 0, 0);
    }
#pragma unroll
    for (int j = 0; j < 6; ++j) {
        __builtin_amdgcn_global_load_lds(
            (const __attribute__((address_space(1))) void*)(BT + j * 1024 + t * 4),
            (__attribute__((address_space(3))) void*)(bs + j * 1024 + t * 4),
            16, 0, 0);
    }
    __syncthreads();   // drains vmcnt(0) before any LDS read

    const float4* xa = (const float4*)(xs + ra * D_N);
    const float4* xb = (const float4*)(xs + (ra + 8) * D_N);
    const float4* bs4 = (const float4*)bs;
    float4 a0 = make_float4(0.f, 0.f, 0.f, 0.f);
    float4 a1 = make_float4(0.f, 0.f, 0.f, 0.f);

#pragma unroll 1
    for (int p = 0; p < 4; ++p) {
        if (p > 0) {
            __syncthreads();   // previous compute done reading bs
#pragma unroll
            for (int j = 0; j < 6; ++j) {
                __builtin_amdgcn_global_load_lds(
                    (const __attribute__((address_space(1))) void*)(BT + p * 6144 + j * 1024 + t * 4),
                    (__attribute__((address_space(3))) void*)(bs + j * 1024 + t * 4),
                    16, 0, 0);
            }
            __syncthreads();   // drain staging
        }
#pragma unroll
        for (int i = 0; i < 48; ++i) {
            float4 bb = bs4[i * 32 + r];
            float4 x0 = xa[p * 48 + i];
            float4 x1 = xb[p * 48 + i];
            a0.x = fmaf(x0.x, bb.x, a0.x); a0.y = fmaf(x0.y, bb.y, a0.y);
            a0.z = fmaf(x0.z, bb.z, a0.z); a0.w = fmaf(x0.w, bb.w, a0.w);
            a1.x = fmaf(x1.x, bb.x, a1.x); a1.y = fmaf(x1.y, bb.y, a1.y);
            a1.z = fmaf(x1.z, bb.z, a1.z); a1.w = fmaf(x1.w, bb.w, a1.w);
        }
    }
    y[(b0 + ra) * R_N + r] = (a0.x + a0.y) + (a0.z + a0.w);
    y[(b0 + ra + 8) * R_N + r] = (a1.x + a1.y) + (a1.z + a1.w);

    // xnorm partials from LDS (same bits as global x): (row,r) sums d = r+32q, q
    // ascending; then serial r2-ascending combine — chain order IDENTICAL to R4.
    const float* xr0 = xs + ra * D_N + r;
    const float* xr1 = xs + (ra + 8) * D_N + r;
    double nv0 = 0.0, nv1 = 0.0;
#pragma unroll
    for (int q = 0; q < 24; ++q) {
        double v0 = (double)xr0[32 * q];
        double v1 = (double)xr1[32 * q];
        nv0 += v0 * v0; nv1 += v1 * v1;
    }
    normred[ra][r] = nv0; normred[ra + 8][r] = nv1;
    __syncthreads();
    if (t < 16) {
        double s = 0.0;
#pragma unroll
        for (int r2 = 0; r2 < 32; ++r2) s += normred[t][r2];
        A64[b0 + t] = s;
    }
}

// ---------------- P[b,k] = h_k - 2 y_b.A_k + fused min/max partials  [bitwise == R4] ----------------
__global__ __launch_bounds__(256) void k_pgemm(const float* __restrict__ Am,
                                               const float* __restrict__ y,
                                               const float* __restrict__ hf,
                                               const double* __restrict__ A64,
                                               float* __restrict__ P,
                                               double* __restrict__ mmpart) {
    __shared__ float As[256][33];
    __shared__ float ys[32][32];
    __shared__ double a64s[32];
    __shared__ double smn[256], smx[256];
    int t = threadIdx.x;
    int k0 = blockIdx.x * 256, b0 = blockIdx.y * 32;
    for (int i = t; i < 256 * 32; i += 256) As[i >> 5][i & 31] = Am[(long)(k0 + (i >> 5)) * R_N + (i & 31)];
    for (int i = t; i < 32 * 32; i += 256) ys[i >> 5][i & 31] = y[(long)(b0 + (i >> 5)) * R_N + (i & 31)];
    if (t < 32) a64s[t] = A64[b0 + t];
    __syncthreads();
    int k = k0 + t;
    float ar[32];
#pragma unroll
    for (int r = 0; r < 32; ++r) ar[r] = As[t][r];
    float hk = hf[k];
    double mn = 1e300, mx = -1e300;
#pragma unroll 4
    for (int b = 0; b < 32; ++b) {
        float dot = 0.f;
#pragma unroll
        for (int r = 0; r < 32; ++r) dot = fmaf(ys[b][r], ar[r], dot);
        float p = fmaf(-2.f, dot, hk);
        P[(long)(b0 + b) * K_N + k] = p;
        double dv = a64s[b] + (double)p;
        mn = fmin(mn, dv); mx = fmax(mx, dv);
    }
    smn[t] = mn; smx[t] = mx; __syncthreads();
    for (int s = 128; s > 0; s >>= 1) {
        if (t < s) { smn[t] = fmin(smn[t], smn[t + s]); smx[t] = fmax(smx[t], smx[t + s]); }
        __syncthreads();
    }
    if (t == 0) {
        int bid = blockIdx.y * gridDim.x + blockIdx.x;
        mmpart[2 * bid] = smn[0]; mmpart[2 * bid + 1] = smx[0];
    }
}

// ---------------- minmax reduce -> sc  [== R4 values; gamma init moved to k_colsum] ----------------
__global__ __launch_bounds__(256) void k_minmax2(const double* __restrict__ part,
                                                 double* __restrict__ sc, int nblk) {
    int t = threadIdx.x;
    double mn = 1e300, mx = -1e300;
    for (int i = t; i < nblk; i += 256) {
        mn = fmin(mn, part[2 * i]); mx = fmax(mx, part[2 * i + 1]);
    }
    __shared__ double smn[256], smx[256];
    smn[t] = mn; smx[t] = mx; __syncthreads();
    for (int s = 128; s > 0; s >>= 1) {
        if (t < s) { smn[t] = fmin(smn[t], smn[t + s]); smx[t] = fmax(smx[t], smx[t + s]); }
        __syncthreads();
    }
    if (t == 0) {
        double mid = (smx[0] + smn[0]) * 0.5;
        double ampl = smx[0] - mid + 1e-5;
        sc[0] = mid; sc[1] = ampl; sc[2] = smn[0];
        sc[3] = 1.0 / (0.01 * ampl);   // beta
    }
}

// ---------------- first colsum (c0), gamma computed in-block  [bitwise == R4] ----------------
__global__ __launch_bounds__(256) void k_colsum(const float* __restrict__ P,
                                                const double* __restrict__ A64,
                                                const double* __restrict__ sc,
                                                float* __restrict__ part) {
    __shared__ float gs[64];
    int t = threadIdx.x;
    int k = blockIdx.x * 256 + t;
    int b0 = blockIdx.y * 64;
    if (t < 64) {
        double bet = sc[3], mnv = sc[2];
        gs[t] = (float)(bet * (mnv - A64[b0 + t]));
    }
    __syncthreads();
    float betaf = (float)sc[3];
    float s0 = 0.f, s1 = 0.f, s2 = 0.f, s3 = 0.f;
#pragma unroll
    for (int j = 0; j < 64; j += 4) {
        s0 += __expf(gs[j]     - betaf * P[(long)(b0 + j)     * K_N + k]);
        s1 += __expf(gs[j + 1] - betaf * P[(long)(b0 + j + 1) * K_N + k]);
        s2 += __expf(gs[j + 2] - betaf * P[(long)(b0 + j + 2) * K_N + k]);
        s3 += __expf(gs[j + 3] - betaf * P[(long)(b0 + j + 3) * K_N + k]);
    }
    part[(long)blockIdx.y * K_N + k] = (s0 + s1) + (s2 + s3);
}

__global__ __launch_bounds__(256) void k_colsum2(const float* __restrict__ part,
                                                 double* __restrict__ lnr64,
                                                 float* __restrict__ lnrf) {
    int k = blockIdx.x * 256 + threadIdx.x;
    double s = 0.0;
#pragma unroll 4
    for (int c = 0; c < 128; ++c) s += (double)part[(long)c * K_N + k];
    double l = -log(s);
    lnr64[k] = l; lnrf[k] = (float)l;
}

// ---------------- fused rowsum_i + colsum_{i+1}: ONE pass over P ----------------
// R6: 256 threads/block, each thread carries TWO virtual columns-groups:
// vt_a = t (group w=t>>6), vt_b = t+256 (group w+4), same lane l=t&63.
// The shfl-xor butterfly yields the value of a FIXED balanced binary tree over the
// 64 lane-partials (IEEE add is commutative), so re-mapping vt->thread preserves
// bits exactly as long as (group, lane) coordinates are preserved — they are.
// Two independent shuffle chains per thread (ILP 2); double-buffered wred -> ONE
// barrier per row (was 2); ~55 VGPR -> high occupancy. Bitwise == R4.
__global__ __launch_bounds__(256) void k_fused(const float* __restrict__ P,
                                               const float* __restrict__ lnrf,
                                               const double* __restrict__ sc,
                                               float* __restrict__ part) {
    __shared__ double wred[2][8];
    int t = threadIdx.x, l = t & 63, w = t >> 6;       // w = 0..3
    float betaf = (float)sc[3];
    int ka = 3 + 4 * t;                                // vt_a = t     (always < 511)
    int tb = t + 256;                                  // vt_b
    int kb = 3 + 4 * tb;
    float lnA0 = lnrf[ka], lnA1 = lnrf[ka + 1], lnA2 = lnrf[ka + 2], lnA3 = lnrf[ka + 3];
    float lnB0, lnB1, lnB2, lnB3;
    if (tb < 511) { lnB0 = lnrf[kb]; lnB1 = lnrf[kb + 1]; lnB2 = lnrf[kb + 2]; lnB3 = lnrf[kb + 3]; }
    else          { lnB0 = lnrf[0];  lnB1 = lnrf[1];      lnB2 = lnrf[2];      lnB3 = lnrf[2047]; }
    float4 accA = make_float4(0.f, 0.f, 0.f, 0.f);
    float4 accB = make_float4(0.f, 0.f, 0.f, 0.f);
    long rowbase = (long)blockIdx.x * 16;
#pragma unroll 1
    for (int rr = 0; rr < 16; ++rr) {
        const float* row = P + (rowbase + rr) * K_N;
        float4 pa = *(const float4*)(row + ka);
        float4 pb;
        if (tb < 511) {
            pb = *(const float4*)(row + kb);
        } else {
            pb.x = row[0]; pb.y = row[1]; pb.z = row[2]; pb.w = row[2047];
        }
        float ea0 = __expf(lnA0 - betaf * pa.x);
        float ea1 = __expf(lnA1 - betaf * pa.y);
        float ea2 = __expf(lnA2 - betaf * pa.z);
        float ea3 = __expf(lnA3 - betaf * pa.w);
        float eb0 = __expf(lnB0 - betaf * pb.x);
        float eb1 = __expf(lnB1 - betaf * pb.y);
        float eb2 = __expf(lnB2 - betaf * pb.z);
        float eb3 = __expf(lnB3 - betaf * pb.w);
        double sa = (double)((ea0 + ea1) + (ea2 + ea3));
        double sb = (double)((eb0 + eb1) + (eb2 + eb3));
#pragma unroll
        for (int off = 1; off < 64; off <<= 1) {       // two independent chains
            sa += __shfl_xor(sa, off, 64);
            sb += __shfl_xor(sb, off, 64);
        }
        const int buf = rr & 1;
        if (l == 0) { wred[buf][w] = sa; wred[buf][w + 4] = sb; }
        __syncthreads();
        // WAR safe: next write to wred[buf] happens 2 barriers later.
        double ss = ((wred[buf][0] + wred[buf][1]) + (wred[buf][2] + wred[buf][3]))
                  + ((wred[buf][4] + wred[buf][5]) + (wred[buf][6] + wred[buf][7]));
        float gf = (float)(-log(ss));
        accA.x += __expf(gf - betaf * pa.x);
        accA.y += __expf(gf - betaf * pa.y);
        accA.z += __expf(gf - betaf * pa.z);
        accA.w += __expf(gf - betaf * pa.w);
        accB.x += __expf(gf - betaf * pb.x);
        accB.y += __expf(gf - betaf * pb.y);
        accB.z += __expf(gf - betaf * pb.z);
        accB.w += __expf(gf - betaf * pb.w);
    }
    // slot layout unchanged: vt<511 -> slots 4vt..4vt+3; vt=511 -> slots 2044..2047
    float4* op = (float4*)(part + (long)blockIdx.x * K_N);
    op[t] = accA;
    op[tb] = accB;
}

// reduce fused partials -> lnr (wave per k, deterministic)
__global__ __launch_bounds__(512) void k_freduce(const float* __restrict__ part,
                                                 double* __restrict__ lnr64,
                                                 float* __restrict__ lnrf) {
    int t = threadIdx.x, l = t & 63, w = t >> 6;
    int k = blockIdx.x * 8 + w;
    int slot = (k >= 3 && k < 2047) ? (k - 3) : (k < 3 ? 2044 + k : 2047);
    double s = 0.0;
#pragma unroll
    for (int j = 0; j < 8; ++j)
        s += (double)part[(long)(l + 64 * j) * K_N + slot];
#pragma unroll
    for (int off = 1; off < 64; off <<= 1) s += __shfl_xor(s, off, 64);
    if (l == 0) { double v = -log(s); lnr64[k] = v; lnrf[k] = (float)v; }
}

// ---------------- final: wave per row — hoisted loads, argmax(f64), dc in place,
// loss via ||e-x||^2 = A64[b] + P[b,bi] (P recovered from dec), gather emb ----------------
__global__ __launch_bounds__(512) void k_final(const double* __restrict__ lnr64,
                                               const double* __restrict__ sc,
                                               const double* __restrict__ A64,
                                               const float* __restrict__ emb,
                                               float* __restrict__ out,
                                               double* __restrict__ lossp) {
    int t = threadIdx.x, l = t & 63, w = t >> 6;
    long b = (long)blockIdx.x * 8 + w;
    float* row = out + OUT_DC + b * K_N;     // P in, dc out (disjoint per wave)
    double beta = sc[3], mid = sc[0], inva = 1.0 / sc[1];
    double a64b = A64[b];
    // ---- hoist ALL loads before any store (avoid alias serialization) ----
    float pe = 0.f;
    if (l < 3)   pe = row[l];
    if (l == 63) pe = row[2047];
    float4 pv[8];
#pragma unroll
    for (int c = 0; c < 8; ++c) {
        int i = l + 64 * c;
        if (i < 511) pv[c] = *(const float4*)(row + 3 + 4 * i);
    }
    // ---- argmax (in-lane ascending k -> first-max) + dc stores ----
    double best = -1e300; int bi = 1 << 30;
    if (l < 3) {
        double p = (double)pe;
        double dec = lnr64[l] - beta * p;
        if (dec > best) { best = dec; bi = l; }
        row[l] = (float)((a64b + p - mid) * inva);
    }
#pragma unroll
    for (int c = 0; c < 8; ++c) {
        int i = l + 64 * c;
        if (i < 511) {
            int k = 3 + 4 * i;
            double p0 = pv[c].x, p1 = pv[c].y, p2 = pv[c].z, p3 = pv[c].w;
            double d0 = lnr64[k] - beta * p0;
            double d1 = lnr64[k + 1] - beta * p1;
            double d2 = lnr64[k + 2] - beta * p2;
            double d3 = lnr64[k + 3] - beta * p3;
            if (d0 > best) { best = d0; bi = k; }
            if (d1 > best) { best = d1; bi = k + 1; }
            if (d2 > best) { best = d2; bi = k + 2; }
            if (d3 > best) { best = d3; bi = k + 3; }
            float4 dcv;
            dcv.x = (float)((a64b + p0 - mid) * inva);
            dcv.y = (float)((a64b + p1 - mid) * inva);
            dcv.z = (float)((a64b + p2 - mid) * inva);
            dcv.w = (float)((a64b + p3 - mid) * inva);
            *(float4*)(row + k) = dcv;
        }
    }
    if (l == 63) {
        double p = (double)pe;
        double dec = lnr64[2047] - beta * p;
        if (dec > best) { best = dec; bi = 2047; }
        row[2047] = (float)((a64b + p - mid) * inva);
    }
#pragma unroll
    for (int off = 1; off < 64; off <<= 1) {                   // first-max: min idx on ties
        double ov = __shfl_xor(best, off, 64);
        int oi = __shfl_xor(bi, off, 64);
        if (ov > best || (ov == best && oi < bi)) { best = ov; bi = oi; }
    }
    if (l == 0) {
        out[OUT_IDX + b] = (float)bi;
        // ||e_bi - x_b||^2 = A64[b] + P[b,bi]; P recovered: dec = lnr - beta*P
        double prec = (lnr64[bi] - best) / beta;
        lossp[b] = a64b + prec;
    }
    // gather emb -> x_q
    const float4* E4 = (const float4*)(emb + (long)bi * D_N);
    float4* O4 = (float4*)(out + OUT_XQ + b * D_N);
#pragma unroll
    for (int i = 0; i < 3; ++i) O4[i * 64 + l] = E4[i * 64 + l];
}

__global__ __launch_bounds__(1024) void k_loss2(const double* __restrict__ lossp,
                                                float* __restrict__ out) {
    __shared__ double red[1024];
    int t = threadIdx.x;
    double s = 0.0;
#pragma unroll
    for (int j = 0; j < 8; ++j) s += lossp[t + 1024 * j];
    red[t] = s; __syncthreads();
    for (int st = 512; st > 0; st >>= 1) { if (t < st) red[t] += red[t + st]; __syncthreads(); }
    if (t == 0) out[OUT_LOSS] = (float)(red[0] * 1.25 / (double)((long)B_N * D_N));
}

extern "C" void kernel_launch(void* const* d_in, const int* in_sizes, int n_in,
                              void* d_out, int out_size, void* d_ws, size_t ws_size,
                              hipStream_t stream) {
    const float* x  = (const float*)d_in[0];   // [8192,768]
    const float* Am = (const float*)d_in[1];   // [2048,32]
    const float* Bm = (const float*)d_in[2];   // [32,768]
    float* out = (float*)d_out;
    float* P = out + OUT_DC;                   // P lives in dc region; k_final converts in place

    char* ws = (char*)d_ws;
    float*  emb     = (float*)(ws);                 // 6,291,456 B
    // 4 MB pool at +6291456: y (1 MB, dead after pgemm) | cs_part (1 MB, dead after c0's
    // colsum2) | 2 MB spare — reused as fpart [512][2048] f32 by k_fused/k_freduce.
    // BT (96 KB) overlays the cs_part region: written inside k_emb, dead after k_ygemm,
    // long before k_colsum first writes cs_part.
    float*  y       = (float*)(ws + 6291456);       // 1,048,576 B
    float*  cs_part = (float*)(ws + 7340032);       // 128*2048*4 = 1,048,576 B
    float*  BTg     = (float*)(ws + 7340032);       // 98,304 B (overlays cs_part)
    float*  fpart   = (float*)(ws + 6291456);       // 512*2048*4 = 4,194,304 B (overlays y+cs_part)
    double* A64     = (double*)(ws + 10485760);     // 65,536 B
    float*  hf      = (float*)(ws + 10551296);      // 8,192 B
    double* lnr64   = (double*)(ws + 10592256);     // 16,384 B
    float*  lnrf    = (float*)(ws + 10608640);      // 8,192 B
    double* mmpart  = (double*)(ws + 10616832);     // 2048*2*8 = 32,768 B
    double* sc      = (double*)(ws + 10649600);     // 4 doubles
    double* lossp   = (double*)(ws + 10649856);     // 8192*8 = 65,536 B
    // total ws use ~10.7 MB

    k_emb<<<K_N, 256, 0, stream>>>(Am, Bm, emb, hf, BTg);
    k_ygemm<<<B_N / 16, 256, 0, stream>>>(x, BTg, y, A64);

    dim3 gp(K_N / 256, B_N / 32);
    k_pgemm<<<gp, 256, 0, stream>>>(Am, y, hf, A64, P, mmpart);
    k_minmax2<<<1, 256, 0, stream>>>(mmpart, sc, 2048);

    // c0 (colsum with gamma0), then 5 fused (rowsum_i + colsum_{i+1}) passes:
    // total colsum x6 / rowsum x5 == R4's schedule; contraction ~0.022/cycle,
    // residual ~2e-10 << ~1e-6 decision gap.
    dim3 ga(K_N / 256, 128);
    k_colsum<<<ga, 256, 0, stream>>>(P, A64, sc, cs_part);
    k_colsum2<<<K_N / 256, 256, 0, stream>>>(cs_part, lnr64, lnrf);
    for (int it = 0; it < 5; ++it) {
        k_fused<<<512, 256, 0, stream>>>(P, lnrf, sc, fpart);
        k_freduce<<<256, 512, 0, stream>>>(fpart, lnr64, lnrf);
    }

    k_final<<<B_N / 8, 512, 0, stream>>>(lnr64, sc, A64, emb, out, lossp);
    k_loss2<<<1, 1024, 0, stream>>>(lossp, out);
}

// Round 7
// 381.132 us; speedup vs baseline: 1.3337x; 1.0188x over previous
//
#include <hip/hip_runtime.h>
#include <math.h>

// Problem constants
#define B_N 8192
#define K_N 2048
#define D_N 768
#define R_N 32

// d_out element offsets: [x_q_st | loss | indices | dc]
#define OUT_XQ   0L
#define OUT_LOSS 6291456L
#define OUT_IDX  6291457L
#define OUT_DC   6299649L   // odd -> dc/P rows are 4B-aligned only; k==3 (mod 4) is 16B-aligned

// ---------------- emb = A @ B (f64 accumulate), h_k = ||e_k||^2  [bitwise == R4]
// + folded BT pack (blocks 0..95): BT4[i*32+r] = float4(B[r][4i..4i+3]) ----------------
__global__ __launch_bounds__(256) void k_emb(const float* __restrict__ A,
                                             const float* __restrict__ Bm,
                                             float* __restrict__ emb,
                                             float* __restrict__ hf,
                                             float* __restrict__ BT) {
    int k = blockIdx.x, t = threadIdx.x;
    if (k < 96) {   // BT pack, independent of the rest
        int j = k * 256 + t;
        int i = j >> 7;
        int rc = j & 127;
        int r = rc >> 2, c = rc & 3;
        BT[j] = Bm[r * D_N + 4 * i + c];
    }
    __shared__ float a_s[R_N];
    if (t < R_N) a_s[t] = A[k * R_N + t];
    __syncthreads();
    double hpart = 0.0;
    for (int d = t; d < D_N; d += 256) {
        double e = 0.0;
#pragma unroll
        for (int r = 0; r < R_N; ++r) e += (double)a_s[r] * (double)Bm[r * D_N + d];
        float ef = (float)e;
        emb[(long)k * D_N + d] = ef;
        hpart += (double)ef * (double)ef;
    }
    __shared__ double red[256];
    red[t] = hpart; __syncthreads();
    for (int s = 128; s > 0; s >>= 1) { if (t < s) red[t] += red[t + s]; __syncthreads(); }
    if (t == 0) hf[k] = (float)red[0];
}

// ---------------- y = x @ B^T [bitwise == R4] + fused ||x_b||^2 (f64) ----------------
// 16 rows/block, 2 rows per lane-half (2 accs); x + B quarters staged via
// global_load_lds. Per-row FMA chain (i ascending via p*48+i, x/y/z/w) and norm
// order IDENTICAL to R4 -> y and A64 bitwise unchanged.
__global__ __launch_bounds__(256) void k_ygemm(const float* __restrict__ x,
                                               const float* __restrict__ BT,
                                               float* __restrict__ y,
                                               double* __restrict__ A64) {
    __shared__ __align__(16) float xs[16 * D_N];     // 48 KB
    __shared__ __align__(16) float bs[48 * 128];     // 24 KB = quarter of BT
    __shared__ double normred[16][32];
    int t = threadIdx.x;
    long b0 = (long)blockIdx.x * 16;
    int h = (t >> 5) & 1, r = t & 31, w = t >> 6;
    int ra = 2 * w + h;                              // 0..7; rows ra and ra+8

    // ---- stage x tile (contiguous 48 KB) + B quarter 0, async global->LDS ----
    const float* xsrc = x + b0 * D_N;
#pragma unroll
    for (int j = 0; j < 12; ++j) {
        __builtin_amdgcn_global_load_lds(
            (const __attribute__((address_space(1))) void*)(xsrc + j * 1024 + t * 4),
            (__attribute__((address_space(3))) void*)(xs + j * 1024 + t * 4),
            16, 0, 0);
    }
#pragma unroll
    for (int j = 0; j < 6; ++j) {
        __builtin_amdgcn_global_load_lds(
            (const __attribute__((address_space(1))) void*)(BT + j * 1024 + t * 4),
            (__attribute__((address_space(3))) void*)(bs + j * 1024 + t * 4),
            16, 0, 0);
    }
    __syncthreads();   // drains vmcnt(0) before any LDS read

    const float4* xa = (const float4*)(xs + ra * D_N);
    const float4* xb = (const float4*)(xs + (ra + 8) * D_N);
    const float4* bs4 = (const float4*)bs;
    float4 a0 = make_float4(0.f, 0.f, 0.f, 0.f);
    float4 a1 = make_float4(0.f, 0.f, 0.f, 0.f);

#pragma unroll 1
    for (int p = 0; p < 4; ++p) {
        if (p > 0) {
            __syncthreads();   // previous compute done reading bs
#pragma unroll
            for (int j = 0; j < 6; ++j) {
                __builtin_amdgcn_global_load_lds(
                    (const __attribute__((address_space(1))) void*)(BT + p * 6144 + j * 1024 + t * 4),
                    (__attribute__((address_space(3))) void*)(bs + j * 1024 + t * 4),
                    16, 0, 0);
            }
            __syncthreads();   // drain staging
        }
#pragma unroll
        for (int i = 0; i < 48; ++i) {
            float4 bb = bs4[i * 32 + r];
            float4 x0 = xa[p * 48 + i];
            float4 x1 = xb[p * 48 + i];
            a0.x = fmaf(x0.x, bb.x, a0.x); a0.y = fmaf(x0.y, bb.y, a0.y);
            a0.z = fmaf(x0.z, bb.z, a0.z); a0.w = fmaf(x0.w, bb.w, a0.w);
            a1.x = fmaf(x1.x, bb.x, a1.x); a1.y = fmaf(x1.y, bb.y, a1.y);
            a1.z = fmaf(x1.z, bb.z, a1.z); a1.w = fmaf(x1.w, bb.w, a1.w);
        }
    }
    y[(b0 + ra) * R_N + r] = (a0.x + a0.y) + (a0.z + a0.w);
    y[(b0 + ra + 8) * R_N + r] = (a1.x + a1.y) + (a1.z + a1.w);

    // xnorm partials from LDS (same bits as global x): (row,r) sums d = r+32q, q
    // ascending; then serial r2-ascending combine — chain order IDENTICAL to R4.
    const float* xr0 = xs + ra * D_N + r;
    const float* xr1 = xs + (ra + 8) * D_N + r;
    double nv0 = 0.0, nv1 = 0.0;
#pragma unroll
    for (int q = 0; q < 24; ++q) {
        double v0 = (double)xr0[32 * q];
        double v1 = (double)xr1[32 * q];
        nv0 += v0 * v0; nv1 += v1 * v1;
    }
    normred[ra][r] = nv0; normred[ra + 8][r] = nv1;
    __syncthreads();
    if (t < 16) {
        double s = 0.0;
#pragma unroll
        for (int r2 = 0; r2 < 32; ++r2) s += normred[t][r2];
        A64[b0 + t] = s;
    }
}

// ---------------- P[b,k] = h_k - 2 y_b.A_k + fused min/max partials  [bitwise == R4] ----------------
__global__ __launch_bounds__(256) void k_pgemm(const float* __restrict__ Am,
                                               const float* __restrict__ y,
                                               const float* __restrict__ hf,
                                               const double* __restrict__ A64,
                                               float* __restrict__ P,
                                               double* __restrict__ mmpart) {
    __shared__ float As[256][33];
    __shared__ float ys[32][32];
    __shared__ double a64s[32];
    __shared__ double smn[256], smx[256];
    int t = threadIdx.x;
    int k0 = blockIdx.x * 256, b0 = blockIdx.y * 32;
    for (int i = t; i < 256 * 32; i += 256) As[i >> 5][i & 31] = Am[(long)(k0 + (i >> 5)) * R_N + (i & 31)];
    for (int i = t; i < 32 * 32; i += 256) ys[i >> 5][i & 31] = y[(long)(b0 + (i >> 5)) * R_N + (i & 31)];
    if (t < 32) a64s[t] = A64[b0 + t];
    __syncthreads();
    int k = k0 + t;
    float ar[32];
#pragma unroll
    for (int r = 0; r < 32; ++r) ar[r] = As[t][r];
    float hk = hf[k];
    double mn = 1e300, mx = -1e300;
#pragma unroll 4
    for (int b = 0; b < 32; ++b) {
        float dot = 0.f;
#pragma unroll
        for (int r = 0; r < 32; ++r) dot = fmaf(ys[b][r], ar[r], dot);
        float p = fmaf(-2.f, dot, hk);
        P[(long)(b0 + b) * K_N + k] = p;
        double dv = a64s[b] + (double)p;
        mn = fmin(mn, dv); mx = fmax(mx, dv);
    }
    smn[t] = mn; smx[t] = mx; __syncthreads();
    for (int s = 128; s > 0; s >>= 1) {
        if (t < s) { smn[t] = fmin(smn[t], smn[t + s]); smx[t] = fmax(smx[t], smx[t + s]); }
        __syncthreads();
    }
    if (t == 0) {
        int bid = blockIdx.y * gridDim.x + blockIdx.x;
        mmpart[2 * bid] = smn[0]; mmpart[2 * bid + 1] = smx[0];
    }
}

// ---------------- minmax reduce -> sc  [== R4 values; gamma init moved to k_colsum] ----------------
__global__ __launch_bounds__(256) void k_minmax2(const double* __restrict__ part,
                                                 double* __restrict__ sc, int nblk) {
    int t = threadIdx.x;
    double mn = 1e300, mx = -1e300;
    for (int i = t; i < nblk; i += 256) {
        mn = fmin(mn, part[2 * i]); mx = fmax(mx, part[2 * i + 1]);
    }
    __shared__ double smn[256], smx[256];
    smn[t] = mn; smx[t] = mx; __syncthreads();
    for (int s = 128; s > 0; s >>= 1) {
        if (t < s) { smn[t] = fmin(smn[t], smn[t + s]); smx[t] = fmax(smx[t], smx[t + s]); }
        __syncthreads();
    }
    if (t == 0) {
        double mid = (smx[0] + smn[0]) * 0.5;
        double ampl = smx[0] - mid + 1e-5;
        sc[0] = mid; sc[1] = ampl; sc[2] = smn[0];
        sc[3] = 1.0 / (0.01 * ampl);   // beta
    }
}

// ---------------- first colsum (c0), gamma computed in-block  [bitwise == R4] ----------------
__global__ __launch_bounds__(256) void k_colsum(const float* __restrict__ P,
                                                const double* __restrict__ A64,
                                                const double* __restrict__ sc,
                                                float* __restrict__ part) {
    __shared__ float gs[64];
    int t = threadIdx.x;
    int k = blockIdx.x * 256 + t;
    int b0 = blockIdx.y * 64;
    if (t < 64) {
        double bet = sc[3], mnv = sc[2];
        gs[t] = (float)(bet * (mnv - A64[b0 + t]));
    }
    __syncthreads();
    float betaf = (float)sc[3];
    float s0 = 0.f, s1 = 0.f, s2 = 0.f, s3 = 0.f;
#pragma unroll
    for (int j = 0; j < 64; j += 4) {
        s0 += __expf(gs[j]     - betaf * P[(long)(b0 + j)     * K_N + k]);
        s1 += __expf(gs[j + 1] - betaf * P[(long)(b0 + j + 1) * K_N + k]);
        s2 += __expf(gs[j + 2] - betaf * P[(long)(b0 + j + 2) * K_N + k]);
        s3 += __expf(gs[j + 3] - betaf * P[(long)(b0 + j + 3) * K_N + k]);
    }
    part[(long)blockIdx.y * K_N + k] = (s0 + s1) + (s2 + s3);
}

__global__ __launch_bounds__(256) void k_colsum2(const float* __restrict__ part,
                                                 double* __restrict__ lnr64,
                                                 float* __restrict__ lnrf) {
    int k = blockIdx.x * 256 + threadIdx.x;
    double s = 0.0;
#pragma unroll 4
    for (int c = 0; c < 128; ++c) s += (double)part[(long)c * K_N + k];
    double l = -log(s);
    lnr64[k] = l; lnrf[k] = (float)l;
}

// ---------------- fused rowsum_i + colsum_{i+1}: ONE pass over P ----------------
// R7: two-row software pipeline (T15 pattern). Each iteration overlaps TWO
// independent chains: (a) load+exp+shfl of row rr+1 (publishes wred[buf^1]),
// (b) finish of row rr (combine wred[buf] + log + acc-exp) from named regs
// paC/pbC. One barrier per row, same wred double-buffer, same add/shfl/log
// operand order as R6 -> bitwise identical. ~+16 VGPR, no dynamic indexing.
#define FLOAD(pa, pb, rr) do {                                              \
    const float* row_ = P + (rowbase + (rr)) * K_N;                         \
    pa = *(const float4*)(row_ + ka);                                       \
    if (tb < 511) { pb = *(const float4*)(row_ + kb); }                     \
    else { pb.x = row_[0]; pb.y = row_[1]; pb.z = row_[2]; pb.w = row_[2047]; } \
} while (0)

#define FPART(pa, pb, sa, sb) do {                                          \
    float ea0 = __expf(lnA0 - betaf * pa.x);                                \
    float ea1 = __expf(lnA1 - betaf * pa.y);                                \
    float ea2 = __expf(lnA2 - betaf * pa.z);                                \
    float ea3 = __expf(lnA3 - betaf * pa.w);                                \
    float eb0 = __expf(lnB0 - betaf * pb.x);                                \
    float eb1 = __expf(lnB1 - betaf * pb.y);                                \
    float eb2 = __expf(lnB2 - betaf * pb.z);                                \
    float eb3 = __expf(lnB3 - betaf * pb.w);                                \
    sa = (double)((ea0 + ea1) + (ea2 + ea3));                               \
    sb = (double)((eb0 + eb1) + (eb2 + eb3));                               \
    _Pragma("unroll")                                                       \
    for (int off = 1; off < 64; off <<= 1) {                                \
        sa += __shfl_xor(sa, off, 64);                                      \
        sb += __shfl_xor(sb, off, 64);                                      \
    }                                                                       \
} while (0)

__global__ __launch_bounds__(256) void k_fused(const float* __restrict__ P,
                                               const float* __restrict__ lnrf,
                                               const double* __restrict__ sc,
                                               float* __restrict__ part) {
    __shared__ double wred[2][8];
    int t = threadIdx.x, l = t & 63, w = t >> 6;       // w = 0..3
    float betaf = (float)sc[3];
    int ka = 3 + 4 * t;                                // vt_a = t (always < 511)
    int tb = t + 256;                                  // vt_b
    int kb = 3 + 4 * tb;
    float lnA0 = lnrf[ka], lnA1 = lnrf[ka + 1], lnA2 = lnrf[ka + 2], lnA3 = lnrf[ka + 3];
    float lnB0, lnB1, lnB2, lnB3;
    if (tb < 511) { lnB0 = lnrf[kb]; lnB1 = lnrf[kb + 1]; lnB2 = lnrf[kb + 2]; lnB3 = lnrf[kb + 3]; }
    else          { lnB0 = lnrf[0];  lnB1 = lnrf[1];      lnB2 = lnrf[2];      lnB3 = lnrf[2047]; }
    float4 accA = make_float4(0.f, 0.f, 0.f, 0.f);
    float4 accB = make_float4(0.f, 0.f, 0.f, 0.f);
    long rowbase = (long)blockIdx.x * 16;

    float4 paC, pbC, paN, pbN;
    double saC, sbC, saN, sbN;
    // prologue: row 0 partials published
    FLOAD(paC, pbC, 0);
    FPART(paC, pbC, saC, sbC);
    if (l == 0) { wred[0][w] = saC; wred[0][w + 4] = sbC; }
    __syncthreads();
#pragma unroll 1
    for (int rr = 0; rr < 16; ++rr) {
        const int buf = rr & 1;
        if (rr < 15) {
            // chain (a): next row's load+exp+shfl -> publish into the other buffer
            FLOAD(paN, pbN, rr + 1);
            FPART(paN, pbN, saN, sbN);
            if (l == 0) { wred[buf ^ 1][w] = saN; wred[buf ^ 1][w + 4] = sbN; }
        }
        // chain (b): finish row rr from wred[buf] (published at previous barrier)
        double ss = ((wred[buf][0] + wred[buf][1]) + (wred[buf][2] + wred[buf][3]))
                  + ((wred[buf][4] + wred[buf][5]) + (wred[buf][6] + wred[buf][7]));
        float gf = (float)(-log(ss));
        accA.x += __expf(gf - betaf * paC.x);
        accA.y += __expf(gf - betaf * paC.y);
        accA.z += __expf(gf - betaf * paC.z);
        accA.w += __expf(gf - betaf * paC.w);
        accB.x += __expf(gf - betaf * pbC.x);
        accB.y += __expf(gf - betaf * pbC.y);
        accB.z += __expf(gf - betaf * pbC.z);
        accB.w += __expf(gf - betaf * pbC.w);
        __syncthreads();   // publishes wred[buf^1]; protects wred[buf] for rewrite
        paC = paN; pbC = pbN;
    }
    // slot layout unchanged: vt<511 -> slots 4vt..4vt+3; vt=511 -> slots 2044..2047
    float4* op = (float4*)(part + (long)blockIdx.x * K_N);
    op[t] = accA;
    op[tb] = accB;
}

// reduce fused partials -> lnr (wave per k, deterministic)
__global__ __launch_bounds__(512) void k_freduce(const float* __restrict__ part,
                                                 double* __restrict__ lnr64,
                                                 float* __restrict__ lnrf) {
    int t = threadIdx.x, l = t & 63, w = t >> 6;
    int k = blockIdx.x * 8 + w;
    int slot = (k >= 3 && k < 2047) ? (k - 3) : (k < 3 ? 2044 + k : 2047);
    double s = 0.0;
#pragma unroll
    for (int j = 0; j < 8; ++j)
        s += (double)part[(long)(l + 64 * j) * K_N + slot];
#pragma unroll
    for (int off = 1; off < 64; off <<= 1) s += __shfl_xor(s, off, 64);
    if (l == 0) { double v = -log(s); lnr64[k] = v; lnrf[k] = (float)v; }
}

// ---------------- final: wave per row — hoisted loads, argmax(f64), dc in place,
// loss via ||e-x||^2 = A64[b] + P[b,bi] (P recovered from dec), gather emb ----------------
__global__ __launch_bounds__(512) void k_final(const double* __restrict__ lnr64,
                                               const double* __restrict__ sc,
                                               const double* __restrict__ A64,
                                               const float* __restrict__ emb,
                                               float* __restrict__ out,
                                               double* __restrict__ lossp) {
    int t = threadIdx.x, l = t & 63, w = t >> 6;
    long b = (long)blockIdx.x * 8 + w;
    float* row = out + OUT_DC + b * K_N;     // P in, dc out (disjoint per wave)
    double beta = sc[3], mid = sc[0], inva = 1.0 / sc[1];
    double a64b = A64[b];
    // ---- hoist ALL loads before any store (avoid alias serialization) ----
    float pe = 0.f;
    if (l < 3)   pe = row[l];
    if (l == 63) pe = row[2047];
    float4 pv[8];
#pragma unroll
    for (int c = 0; c < 8; ++c) {
        int i = l + 64 * c;
        if (i < 511) pv[c] = *(const float4*)(row + 3 + 4 * i);
    }
    // ---- argmax (in-lane ascending k -> first-max) + dc stores ----
    double best = -1e300; int bi = 1 << 30;
    if (l < 3) {
        double p = (double)pe;
        double dec = lnr64[l] - beta * p;
        if (dec > best) { best = dec; bi = l; }
        row[l] = (float)((a64b + p - mid) * inva);
    }
#pragma unroll
    for (int c = 0; c < 8; ++c) {
        int i = l + 64 * c;
        if (i < 511) {
            int k = 3 + 4 * i;
            double p0 = pv[c].x, p1 = pv[c].y, p2 = pv[c].z, p3 = pv[c].w;
            double d0 = lnr64[k] - beta * p0;
            double d1 = lnr64[k + 1] - beta * p1;
            double d2 = lnr64[k + 2] - beta * p2;
            double d3 = lnr64[k + 3] - beta * p3;
            if (d0 > best) { best = d0; bi = k; }
            if (d1 > best) { best = d1; bi = k + 1; }
            if (d2 > best) { best = d2; bi = k + 2; }
            if (d3 > best) { best = d3; bi = k + 3; }
            float4 dcv;
            dcv.x = (float)((a64b + p0 - mid) * inva);
            dcv.y = (float)((a64b + p1 - mid) * inva);
            dcv.z = (float)((a64b + p2 - mid) * inva);
            dcv.w = (float)((a64b + p3 - mid) * inva);
            *(float4*)(row + k) = dcv;
        }
    }
    if (l == 63) {
        double p = (double)pe;
        double dec = lnr64[2047] - beta * p;
        if (dec > best) { best = dec; bi = 2047; }
        row[2047] = (float)((a64b + p - mid) * inva);
    }
#pragma unroll
    for (int off = 1; off < 64; off <<= 1) {                   // first-max: min idx on ties
        double ov = __shfl_xor(best, off, 64);
        int oi = __shfl_xor(bi, off, 64);
        if (ov > best || (ov == best && oi < bi)) { best = ov; bi = oi; }
    }
    if (l == 0) {
        out[OUT_IDX + b] = (float)bi;
        // ||e_bi - x_b||^2 = A64[b] + P[b,bi]; P recovered: dec = lnr - beta*P
        double prec = (lnr64[bi] - best) / beta;
        lossp[b] = a64b + prec;
    }
    // gather emb -> x_q
    const float4* E4 = (const float4*)(emb + (long)bi * D_N);
    float4* O4 = (float4*)(out + OUT_XQ + b * D_N);
#pragma unroll
    for (int i = 0; i < 3; ++i) O4[i * 64 + l] = E4[i * 64 + l];
}

__global__ __launch_bounds__(1024) void k_loss2(const double* __restrict__ lossp,
                                                float* __restrict__ out) {
    __shared__ double red[1024];
    int t = threadIdx.x;
    double s = 0.0;
#pragma unroll
    for (int j = 0; j < 8; ++j) s += lossp[t + 1024 * j];
    red[t] = s; __syncthreads();
    for (int st = 512; st > 0; st >>= 1) { if (t < st) red[t] += red[t + st]; __syncthreads(); }
    if (t == 0) out[OUT_LOSS] = (float)(red[0] * 1.25 / (double)((long)B_N * D_N));
}

extern "C" void kernel_launch(void* const* d_in, const int* in_sizes, int n_in,
                              void* d_out, int out_size, void* d_ws, size_t ws_size,
                              hipStream_t stream) {
    const float* x  = (const float*)d_in[0];   // [8192,768]
    const float* Am = (const float*)d_in[1];   // [2048,32]
    const float* Bm = (const float*)d_in[2];   // [32,768]
    float* out = (float*)d_out;
    float* P = out + OUT_DC;                   // P lives in dc region; k_final converts in place

    char* ws = (char*)d_ws;
    float*  emb     = (float*)(ws);                 // 6,291,456 B
    // 4 MB pool at +6291456: y (1 MB, dead after pgemm) | cs_part (1 MB, dead after c0's
    // colsum2) | 2 MB spare — reused as fpart [512][2048] f32 by k_fused/k_freduce.
    // BT (96 KB) overlays the cs_part region: written inside k_emb, dead after k_ygemm,
    // long before k_colsum first writes cs_part.
    float*  y       = (float*)(ws + 6291456);       // 1,048,576 B
    float*  cs_part = (float*)(ws + 7340032);       // 128*2048*4 = 1,048,576 B
    float*  BTg     = (float*)(ws + 7340032);       // 98,304 B (overlays cs_part)
    float*  fpart   = (float*)(ws + 6291456);       // 512*2048*4 = 4,194,304 B (overlays y+cs_part)
    double* A64     = (double*)(ws + 10485760);     // 65,536 B
    float*  hf      = (float*)(ws + 10551296);      // 8,192 B
    double* lnr64   = (double*)(ws + 10592256);     // 16,384 B
    float*  lnrf    = (float*)(ws + 10608640);      // 8,192 B
    double* mmpart  = (double*)(ws + 10616832);     // 2048*2*8 = 32,768 B
    double* sc      = (double*)(ws + 10649600);     // 4 doubles
    double* lossp   = (double*)(ws + 10649856);     // 8192*8 = 65,536 B
    // total ws use ~10.7 MB

    k_emb<<<K_N, 256, 0, stream>>>(Am, Bm, emb, hf, BTg);
    k_ygemm<<<B_N / 16, 256, 0, stream>>>(x, BTg, y, A64);

    dim3 gp(K_N / 256, B_N / 32);
    k_pgemm<<<gp, 256, 0, stream>>>(Am, y, hf, A64, P, mmpart);
    k_minmax2<<<1, 256, 0, stream>>>(mmpart, sc, 2048);

    // c0 (colsum with gamma0), then 5 fused (rowsum_i + colsum_{i+1}) passes:
    // total colsum x6 / rowsum x5 == R4's schedule; contraction ~0.022/cycle,
    // residual ~2e-10 << ~1e-6 decision gap.
    dim3 ga(K_N / 256, 128);
    k_colsum<<<ga, 256, 0, stream>>>(P, A64, sc, cs_part);
    k_colsum2<<<K_N / 256, 256, 0, stream>>>(cs_part, lnr64, lnrf);
    for (int it = 0; it < 5; ++it) {
        k_fused<<<512, 256, 0, stream>>>(P, lnrf, sc, fpart);
        k_freduce<<<256, 512, 0, stream>>>(fpart, lnr64, lnrf);
    }

    k_final<<<B_N / 8, 512, 0, stream>>>(lnr64, sc, A64, emb, out, lossp);
    k_loss2<<<1, 1024, 0, stream>>>(lossp, out);
}

// Round 8
// 341.673 us; speedup vs baseline: 1.4877x; 1.1155x over previous
//
#include <hip/hip_runtime.h>
#include <math.h>

// Problem constants
#define B_N 8192
#define K_N 2048
#define D_N 768
#define R_N 32

// d_out element offsets: [x_q_st | loss | indices | dc]
#define OUT_XQ   0L
#define OUT_LOSS 6291456L
#define OUT_IDX  6291457L
#define OUT_DC   6299649L   // odd -> dc/P rows are 4B-aligned only; k==3 (mod 4) is 16B-aligned

// ---------------- emb = A @ B (f64 accumulate), h_k = ||e_k||^2  [bitwise == R4]
// + folded BT pack (blocks 0..95): BT4[i*32+r] = float4(B[r][4i..4i+3]) ----------------
__global__ __launch_bounds__(256) void k_emb(const float* __restrict__ A,
                                             const float* __restrict__ Bm,
                                             float* __restrict__ emb,
                                             float* __restrict__ hf,
                                             float* __restrict__ BT) {
    int k = blockIdx.x, t = threadIdx.x;
    if (k < 96) {   // BT pack, independent of the rest
        int j = k * 256 + t;
        int i = j >> 7;
        int rc = j & 127;
        int r = rc >> 2, c = rc & 3;
        BT[j] = Bm[r * D_N + 4 * i + c];
    }
    __shared__ float a_s[R_N];
    if (t < R_N) a_s[t] = A[k * R_N + t];
    __syncthreads();
    double hpart = 0.0;
    for (int d = t; d < D_N; d += 256) {
        double e = 0.0;
#pragma unroll
        for (int r = 0; r < R_N; ++r) e += (double)a_s[r] * (double)Bm[r * D_N + d];
        float ef = (float)e;
        emb[(long)k * D_N + d] = ef;
        hpart += (double)ef * (double)ef;
    }
    __shared__ double red[256];
    red[t] = hpart; __syncthreads();
    for (int s = 128; s > 0; s >>= 1) { if (t < s) red[t] += red[t + s]; __syncthreads(); }
    if (t == 0) hf[k] = (float)red[0];
}

// ---------------- y = x @ B^T [bitwise == R4] + fused ||x_b||^2 (f64) ----------------
__global__ __launch_bounds__(256) void k_ygemm(const float* __restrict__ x,
                                               const float* __restrict__ BT,
                                               float* __restrict__ y,
                                               double* __restrict__ A64) {
    __shared__ __align__(16) float xs[16 * D_N];     // 48 KB
    __shared__ __align__(16) float bs[48 * 128];     // 24 KB = quarter of BT
    __shared__ double normred[16][32];
    int t = threadIdx.x;
    long b0 = (long)blockIdx.x * 16;
    int h = (t >> 5) & 1, r = t & 31, w = t >> 6;
    int ra = 2 * w + h;                              // 0..7; rows ra and ra+8

    const float* xsrc = x + b0 * D_N;
#pragma unroll
    for (int j = 0; j < 12; ++j) {
        __builtin_amdgcn_global_load_lds(
            (const __attribute__((address_space(1))) void*)(xsrc + j * 1024 + t * 4),
            (__attribute__((address_space(3))) void*)(xs + j * 1024 + t * 4),
            16, 0, 0);
    }
#pragma unroll
    for (int j = 0; j < 6; ++j) {
        __builtin_amdgcn_global_load_lds(
            (const __attribute__((address_space(1))) void*)(BT + j * 1024 + t * 4),
            (__attribute__((address_space(3))) void*)(bs + j * 1024 + t * 4),
            16, 0, 0);
    }
    __syncthreads();

    const float4* xa = (const float4*)(xs + ra * D_N);
    const float4* xb = (const float4*)(xs + (ra + 8) * D_N);
    const float4* bs4 = (const float4*)bs;
    float4 a0 = make_float4(0.f, 0.f, 0.f, 0.f);
    float4 a1 = make_float4(0.f, 0.f, 0.f, 0.f);

#pragma unroll 1
    for (int p = 0; p < 4; ++p) {
        if (p > 0) {
            __syncthreads();
#pragma unroll
            for (int j = 0; j < 6; ++j) {
                __builtin_amdgcn_global_load_lds(
                    (const __attribute__((address_space(1))) void*)(BT + p * 6144 + j * 1024 + t * 4),
                    (__attribute__((address_space(3))) void*)(bs + j * 1024 + t * 4),
                    16, 0, 0);
            }
            __syncthreads();
        }
#pragma unroll
        for (int i = 0; i < 48; ++i) {
            float4 bb = bs4[i * 32 + r];
            float4 x0 = xa[p * 48 + i];
            float4 x1 = xb[p * 48 + i];
            a0.x = fmaf(x0.x, bb.x, a0.x); a0.y = fmaf(x0.y, bb.y, a0.y);
            a0.z = fmaf(x0.z, bb.z, a0.z); a0.w = fmaf(x0.w, bb.w, a0.w);
            a1.x = fmaf(x1.x, bb.x, a1.x); a1.y = fmaf(x1.y, bb.y, a1.y);
            a1.z = fmaf(x1.z, bb.z, a1.z); a1.w = fmaf(x1.w, bb.w, a1.w);
        }
    }
    y[(b0 + ra) * R_N + r] = (a0.x + a0.y) + (a0.z + a0.w);
    y[(b0 + ra + 8) * R_N + r] = (a1.x + a1.y) + (a1.z + a1.w);

    const float* xr0 = xs + ra * D_N + r;
    const float* xr1 = xs + (ra + 8) * D_N + r;
    double nv0 = 0.0, nv1 = 0.0;
#pragma unroll
    for (int q = 0; q < 24; ++q) {
        double v0 = (double)xr0[32 * q];
        double v1 = (double)xr1[32 * q];
        nv0 += v0 * v0; nv1 += v1 * v1;
    }
    normred[ra][r] = nv0; normred[ra + 8][r] = nv1;
    __syncthreads();
    if (t < 16) {
        double s = 0.0;
#pragma unroll
        for (int r2 = 0; r2 < 32; ++r2) s += normred[t][r2];
        A64[b0 + t] = s;
    }
}

// ---------------- P[b,k] = h_k - 2 y_b.A_k + fused min/max partials  [bitwise == R4] ----------------
__global__ __launch_bounds__(256) void k_pgemm(const float* __restrict__ Am,
                                               const float* __restrict__ y,
                                               const float* __restrict__ hf,
                                               const double* __restrict__ A64,
                                               float* __restrict__ P,
                                               double* __restrict__ mmpart) {
    __shared__ float As[256][33];
    __shared__ float ys[32][32];
    __shared__ double a64s[32];
    __shared__ double smn[256], smx[256];
    int t = threadIdx.x;
    int k0 = blockIdx.x * 256, b0 = blockIdx.y * 32;
    for (int i = t; i < 256 * 32; i += 256) As[i >> 5][i & 31] = Am[(long)(k0 + (i >> 5)) * R_N + (i & 31)];
    for (int i = t; i < 32 * 32; i += 256) ys[i >> 5][i & 31] = y[(long)(b0 + (i >> 5)) * R_N + (i & 31)];
    if (t < 32) a64s[t] = A64[b0 + t];
    __syncthreads();
    int k = k0 + t;
    float ar[32];
#pragma unroll
    for (int r = 0; r < 32; ++r) ar[r] = As[t][r];
    float hk = hf[k];
    double mn = 1e300, mx = -1e300;
#pragma unroll 4
    for (int b = 0; b < 32; ++b) {
        float dot = 0.f;
#pragma unroll
        for (int r = 0; r < 32; ++r) dot = fmaf(ys[b][r], ar[r], dot);
        float p = fmaf(-2.f, dot, hk);
        P[(long)(b0 + b) * K_N + k] = p;
        double dv = a64s[b] + (double)p;
        mn = fmin(mn, dv); mx = fmax(mx, dv);
    }
    smn[t] = mn; smx[t] = mx; __syncthreads();
    for (int s = 128; s > 0; s >>= 1) {
        if (t < s) { smn[t] = fmin(smn[t], smn[t + s]); smx[t] = fmax(smx[t], smx[t + s]); }
        __syncthreads();
    }
    if (t == 0) {
        int bid = blockIdx.y * gridDim.x + blockIdx.x;
        mmpart[2 * bid] = smn[0]; mmpart[2 * bid + 1] = smx[0];
    }
}

// ---------------- minmax reduce -> sc  [== R4 values] ----------------
__global__ __launch_bounds__(256) void k_minmax2(const double* __restrict__ part,
                                                 double* __restrict__ sc, int nblk) {
    int t = threadIdx.x;
    double mn = 1e300, mx = -1e300;
    for (int i = t; i < nblk; i += 256) {
        mn = fmin(mn, part[2 * i]); mx = fmax(mx, part[2 * i + 1]);
    }
    __shared__ double smn[256], smx[256];
    smn[t] = mn; smx[t] = mx; __syncthreads();
    for (int s = 128; s > 0; s >>= 1) {
        if (t < s) { smn[t] = fmin(smn[t], smn[t + s]); smx[t] = fmax(smx[t], smx[t + s]); }
        __syncthreads();
    }
    if (t == 0) {
        double mid = (smx[0] + smn[0]) * 0.5;
        double ampl = smx[0] - mid + 1e-5;
        sc[0] = mid; sc[1] = ampl; sc[2] = smn[0];
        sc[3] = 1.0 / (0.01 * ampl);   // beta
    }
}

// ---------------- first colsum (c0), gamma computed in-block  [bitwise == R4] ----------------
__global__ __launch_bounds__(256) void k_colsum(const float* __restrict__ P,
                                                const double* __restrict__ A64,
                                                const double* __restrict__ sc,
                                                float* __restrict__ part) {
    __shared__ float gs[64];
    int t = threadIdx.x;
    int k = blockIdx.x * 256 + t;
    int b0 = blockIdx.y * 64;
    if (t < 64) {
        double bet = sc[3], mnv = sc[2];
        gs[t] = (float)(bet * (mnv - A64[b0 + t]));
    }
    __syncthreads();
    float betaf = (float)sc[3];
    float s0 = 0.f, s1 = 0.f, s2 = 0.f, s3 = 0.f;
#pragma unroll
    for (int j = 0; j < 64; j += 4) {
        s0 += __expf(gs[j]     - betaf * P[(long)(b0 + j)     * K_N + k]);
        s1 += __expf(gs[j + 1] - betaf * P[(long)(b0 + j + 1) * K_N + k]);
        s2 += __expf(gs[j + 2] - betaf * P[(long)(b0 + j + 2) * K_N + k]);
        s3 += __expf(gs[j + 3] - betaf * P[(long)(b0 + j + 3) * K_N + k]);
    }
    part[(long)blockIdx.y * K_N + k] = (s0 + s1) + (s2 + s3);
}

__global__ __launch_bounds__(256) void k_colsum2(const float* __restrict__ part,
                                                 double* __restrict__ lnr64,
                                                 float* __restrict__ lnrf) {
    int k = blockIdx.x * 256 + threadIdx.x;
    double s = 0.0;
#pragma unroll 4
    for (int c = 0; c < 128; ++c) s += (double)part[(long)c * K_N + k];
    double l = -log(s);
    lnr64[k] = l; lnrf[k] = (float)l;
}

// ---------------- fused rowsum_i + colsum_{i+1}: ONE pass over P ----------------
// R8: 2-deep load prefetch. Three register sets (C = row rr, N = row rr+1 loaded,
// F = row rr+2 being loaded) rotate each iteration; FPART consumes data loaded two
// iterations earlier, so the P-load latency leaves the per-row critical path
// entirely (R7's 1-deep version exposed it inside chain(a)). All f32/f64 operand
// orders identical to R6/R7 -> bitwise identical output. Static regs only.
#define FLOAD(pa, pb, rr) do {                                              \
    const float* row_ = P + (rowbase + (rr)) * K_N;                         \
    pa = *(const float4*)(row_ + ka);                                       \
    if (tb < 511) { pb = *(const float4*)(row_ + kb); }                     \
    else { pb.x = row_[0]; pb.y = row_[1]; pb.z = row_[2]; pb.w = row_[2047]; } \
} while (0)

#define FPART(pa, pb, sa, sb) do {                                          \
    float ea0 = __expf(lnA0 - betaf * pa.x);                                \
    float ea1 = __expf(lnA1 - betaf * pa.y);                                \
    float ea2 = __expf(lnA2 - betaf * pa.z);                                \
    float ea3 = __expf(lnA3 - betaf * pa.w);                                \
    float eb0 = __expf(lnB0 - betaf * pb.x);                                \
    float eb1 = __expf(lnB1 - betaf * pb.y);                                \
    float eb2 = __expf(lnB2 - betaf * pb.z);                                \
    float eb3 = __expf(lnB3 - betaf * pb.w);                                \
    sa = (double)((ea0 + ea1) + (ea2 + ea3));                               \
    sb = (double)((eb0 + eb1) + (eb2 + eb3));                               \
    _Pragma("unroll")                                                       \
    for (int off = 1; off < 64; off <<= 1) {                                \
        sa += __shfl_xor(sa, off, 64);                                      \
        sb += __shfl_xor(sb, off, 64);                                      \
    }                                                                       \
} while (0)

__global__ __launch_bounds__(256) void k_fused(const float* __restrict__ P,
                                               const float* __restrict__ lnrf,
                                               const double* __restrict__ sc,
                                               float* __restrict__ part) {
    __shared__ double wred[2][8];
    int t = threadIdx.x, l = t & 63, w = t >> 6;       // w = 0..3
    float betaf = (float)sc[3];
    int ka = 3 + 4 * t;                                // vt_a = t (always < 511)
    int tb = t + 256;                                  // vt_b
    int kb = 3 + 4 * tb;
    float lnA0 = lnrf[ka], lnA1 = lnrf[ka + 1], lnA2 = lnrf[ka + 2], lnA3 = lnrf[ka + 3];
    float lnB0, lnB1, lnB2, lnB3;
    if (tb < 511) { lnB0 = lnrf[kb]; lnB1 = lnrf[kb + 1]; lnB2 = lnrf[kb + 2]; lnB3 = lnrf[kb + 3]; }
    else          { lnB0 = lnrf[0];  lnB1 = lnrf[1];      lnB2 = lnrf[2];      lnB3 = lnrf[2047]; }
    float4 accA = make_float4(0.f, 0.f, 0.f, 0.f);
    float4 accB = make_float4(0.f, 0.f, 0.f, 0.f);
    long rowbase = (long)blockIdx.x * 16;

    float4 paC, pbC, paN, pbN, paF, pbF;
    double saC, sbC, saN, sbN;
    // prologue: rows 0 and 1 loaded; row 0 partials published
    FLOAD(paC, pbC, 0);
    FLOAD(paN, pbN, 1);
    FPART(paC, pbC, saC, sbC);
    if (l == 0) { wred[0][w] = saC; wred[0][w + 4] = sbC; }
    __syncthreads();
#pragma unroll 1
    for (int rr = 0; rr < 16; ++rr) {
        const int buf = rr & 1;
        if (rr < 14) FLOAD(paF, pbF, rr + 2);   // issue 2 rows ahead
        if (rr < 15) {
            // chain (a): row rr+1 exp+shfl (its load completed >=1 iter ago)
            FPART(paN, pbN, saN, sbN);
            if (l == 0) { wred[buf ^ 1][w] = saN; wred[buf ^ 1][w + 4] = sbN; }
        }
        // chain (b): finish row rr from wred[buf] (published at previous barrier)
        double ss = ((wred[buf][0] + wred[buf][1]) + (wred[buf][2] + wred[buf][3]))
                  + ((wred[buf][4] + wred[buf][5]) + (wred[buf][6] + wred[buf][7]));
        float gf = (float)(-log(ss));
        accA.x += __expf(gf - betaf * paC.x);
        accA.y += __expf(gf - betaf * paC.y);
        accA.z += __expf(gf - betaf * paC.z);
        accA.w += __expf(gf - betaf * paC.w);
        accB.x += __expf(gf - betaf * pbC.x);
        accB.y += __expf(gf - betaf * pbC.y);
        accB.z += __expf(gf - betaf * pbC.z);
        accB.w += __expf(gf - betaf * pbC.w);
        __syncthreads();   // publishes wred[buf^1]; protects wred[buf] for rewrite
        paC = paN; pbC = pbN;
        paN = paF; pbN = pbF;
    }
    // slot layout unchanged: vt<511 -> slots 4vt..4vt+3; vt=511 -> slots 2044..2047
    float4* op = (float4*)(part + (long)blockIdx.x * K_N);
    op[t] = accA;
    op[tb] = accB;
}

// reduce fused partials -> lnr
// R8: coalesced rewrite (lanes read CONSECUTIVE k -> 4B x 32 contiguous, was 64
// distinct lines/instr). f64 partial-sum tree re-associated (8 segs of 64 rows,
// fixed LDS combine) — f64 reassociation error ~1e-15 rel, 9 orders below the
// ~1e-6 decision gap; final -log in f64 unchanged.
__global__ __launch_bounds__(256) void k_freduce(const float* __restrict__ part,
                                                 double* __restrict__ lnr64,
                                                 float* __restrict__ lnrf) {
    __shared__ double red[8][32];
    int t = threadIdx.x;
    int kk = t & 31, seg = t >> 5;                     // seg 0..7, 64 rows each
    int k = blockIdx.x * 32 + kk;
    int slot = (k >= 3 && k < 2047) ? (k - 3) : (k < 3 ? 2044 + k : 2047);
    const float* pp = part + (long)(seg * 64) * K_N + slot;
    double s = 0.0;
#pragma unroll 8
    for (int j = 0; j < 64; ++j) s += (double)pp[(long)j * K_N];
    red[seg][kk] = s;
    __syncthreads();
    if (t < 32) {
        int k2 = blockIdx.x * 32 + t;
        double v = ((red[0][t] + red[1][t]) + (red[2][t] + red[3][t]))
                 + ((red[4][t] + red[5][t]) + (red[6][t] + red[7][t]));
        double lv = -log(v);
        lnr64[k2] = lv; lnrf[k2] = (float)lv;
    }
}

// ---------------- final: wave per row — hoisted loads, argmax(f64), dc in place,
// loss via ||e-x||^2 = A64[b] + P[b,bi] (P recovered from dec), gather emb ----------------
__global__ __launch_bounds__(512) void k_final(const double* __restrict__ lnr64,
                                               const double* __restrict__ sc,
                                               const double* __restrict__ A64,
                                               const float* __restrict__ emb,
                                               float* __restrict__ out,
                                               double* __restrict__ lossp) {
    int t = threadIdx.x, l = t & 63, w = t >> 6;
    long b = (long)blockIdx.x * 8 + w;
    float* row = out + OUT_DC + b * K_N;     // P in, dc out (disjoint per wave)
    double beta = sc[3], mid = sc[0], inva = 1.0 / sc[1];
    double a64b = A64[b];
    float pe = 0.f;
    if (l < 3)   pe = row[l];
    if (l == 63) pe = row[2047];
    float4 pv[8];
#pragma unroll
    for (int c = 0; c < 8; ++c) {
        int i = l + 64 * c;
        if (i < 511) pv[c] = *(const float4*)(row + 3 + 4 * i);
    }
    double best = -1e300; int bi = 1 << 30;
    if (l < 3) {
        double p = (double)pe;
        double dec = lnr64[l] - beta * p;
        if (dec > best) { best = dec; bi = l; }
        row[l] = (float)((a64b + p - mid) * inva);
    }
#pragma unroll
    for (int c = 0; c < 8; ++c) {
        int i = l + 64 * c;
        if (i < 511) {
            int k = 3 + 4 * i;
            double p0 = pv[c].x, p1 = pv[c].y, p2 = pv[c].z, p3 = pv[c].w;
            double d0 = lnr64[k] - beta * p0;
            double d1 = lnr64[k + 1] - beta * p1;
            double d2 = lnr64[k + 2] - beta * p2;
            double d3 = lnr64[k + 3] - beta * p3;
            if (d0 > best) { best = d0; bi = k; }
            if (d1 > best) { best = d1; bi = k + 1; }
            if (d2 > best) { best = d2; bi = k + 2; }
            if (d3 > best) { best = d3; bi = k + 3; }
            float4 dcv;
            dcv.x = (float)((a64b + p0 - mid) * inva);
            dcv.y = (float)((a64b + p1 - mid) * inva);
            dcv.z = (float)((a64b + p2 - mid) * inva);
            dcv.w = (float)((a64b + p3 - mid) * inva);
            *(float4*)(row + k) = dcv;
        }
    }
    if (l == 63) {
        double p = (double)pe;
        double dec = lnr64[2047] - beta * p;
        if (dec > best) { best = dec; bi = 2047; }
        row[2047] = (float)((a64b + p - mid) * inva);
    }
#pragma unroll
    for (int off = 1; off < 64; off <<= 1) {                   // first-max: min idx on ties
        double ov = __shfl_xor(best, off, 64);
        int oi = __shfl_xor(bi, off, 64);
        if (ov > best || (ov == best && oi < bi)) { best = ov; bi = oi; }
    }
    if (l == 0) {
        out[OUT_IDX + b] = (float)bi;
        double prec = (lnr64[bi] - best) / beta;
        lossp[b] = a64b + prec;
    }
    const float4* E4 = (const float4*)(emb + (long)bi * D_N);
    float4* O4 = (float4*)(out + OUT_XQ + b * D_N);
#pragma unroll
    for (int i = 0; i < 3; ++i) O4[i * 64 + l] = E4[i * 64 + l];
}

__global__ __launch_bounds__(1024) void k_loss2(const double* __restrict__ lossp,
                                                float* __restrict__ out) {
    __shared__ double red[1024];
    int t = threadIdx.x;
    double s = 0.0;
#pragma unroll
    for (int j = 0; j < 8; ++j) s += lossp[t + 1024 * j];
    red[t] = s; __syncthreads();
    for (int st = 512; st > 0; st >>= 1) { if (t < st) red[t] += red[t + st]; __syncthreads(); }
    if (t == 0) out[OUT_LOSS] = (float)(red[0] * 1.25 / (double)((long)B_N * D_N));
}

extern "C" void kernel_launch(void* const* d_in, const int* in_sizes, int n_in,
                              void* d_out, int out_size, void* d_ws, size_t ws_size,
                              hipStream_t stream) {
    const float* x  = (const float*)d_in[0];   // [8192,768]
    const float* Am = (const float*)d_in[1];   // [2048,32]
    const float* Bm = (const float*)d_in[2];   // [32,768]
    float* out = (float*)d_out;
    float* P = out + OUT_DC;                   // P lives in dc region; k_final converts in place

    char* ws = (char*)d_ws;
    float*  emb     = (float*)(ws);                 // 6,291,456 B
    float*  y       = (float*)(ws + 6291456);       // 1,048,576 B
    float*  cs_part = (float*)(ws + 7340032);       // 128*2048*4 = 1,048,576 B
    float*  BTg     = (float*)(ws + 7340032);       // 98,304 B (overlays cs_part)
    float*  fpart   = (float*)(ws + 6291456);       // 512*2048*4 = 4,194,304 B (overlays y+cs_part)
    double* A64     = (double*)(ws + 10485760);     // 65,536 B
    float*  hf      = (float*)(ws + 10551296);      // 8,192 B
    double* lnr64   = (double*)(ws + 10592256);     // 16,384 B
    float*  lnrf    = (float*)(ws + 10608640);      // 8,192 B
    double* mmpart  = (double*)(ws + 10616832);     // 2048*2*8 = 32,768 B
    double* sc      = (double*)(ws + 10649600);     // 4 doubles
    double* lossp   = (double*)(ws + 10649856);     // 8192*8 = 65,536 B
    // total ws use ~10.7 MB

    k_emb<<<K_N, 256, 0, stream>>>(Am, Bm, emb, hf, BTg);
    k_ygemm<<<B_N / 16, 256, 0, stream>>>(x, BTg, y, A64);

    dim3 gp(K_N / 256, B_N / 32);
    k_pgemm<<<gp, 256, 0, stream>>>(Am, y, hf, A64, P, mmpart);
    k_minmax2<<<1, 256, 0, stream>>>(mmpart, sc, 2048);

    // c0 (colsum with gamma0), then 4 fused (rowsum_i + colsum_{i+1}) passes:
    // colsum x5 / rowsum x4. Contraction ~0.022/half-cycle => residual after 4
    // passes ~9e-9, still ~100x below the ~1e-6 decision gap (5 passes gave 2e-10;
    // the 5th bought nothing decision-wise). absmax gate guards this.
    dim3 ga(K_N / 256, 128);
    k_colsum<<<ga, 256, 0, stream>>>(P, A64, sc, cs_part);
    k_colsum2<<<K_N / 256, 256, 0, stream>>>(cs_part, lnr64, lnrf);
    for (int it = 0; it < 4; ++it) {
        k_fused<<<512, 256, 0, stream>>>(P, lnrf, sc, fpart);
        k_freduce<<<K_N / 32, 256, 0, stream>>>(fpart, lnr64, lnrf);
    }

    k_final<<<B_N / 8, 512, 0, stream>>>(lnr64, sc, A64, emb, out, lossp);
    k_loss2<<<1, 1024, 0, stream>>>(lossp, out);
}